// Round 1
// baseline (518.765 us; speedup 1.0000x reference)
//
#include <hip/hip_runtime.h>
#include <stdint.h>

#define BB      8
#define HH      56
#define WWD     56
#define CCH     512
#define NHEADS  8
#define HD      64
#define NWIN    7
#define NREG    49
#define RSZ     64
#define TOPKK   4
#define PPI     (HH*WWD)        // 3136
#define NPIX    (BB*PPI)        // 25088
#define OC      (3*CCH)         // 1536
#define SCALE_F 0.04419417382415922f

typedef unsigned short u16;
typedef u16   u16x8 __attribute__((ext_vector_type(8)));
typedef u16   u16x4 __attribute__((ext_vector_type(4)));
typedef __bf16 b16x8 __attribute__((ext_vector_type(8)));
typedef float f32x4 __attribute__((ext_vector_type(4)));
typedef int   i32x4 __attribute__((ext_vector_type(4)));

__device__ __forceinline__ u16 f2b(float f){
    unsigned u = __builtin_bit_cast(unsigned, f);
    return (u16)((u + 0x7fffu + ((u >> 16) & 1u)) >> 16);   // RNE
}
__device__ __forceinline__ float b2f(u16 h){
    return __builtin_bit_cast(float, (unsigned)h << 16);
}
__device__ __forceinline__ f32x4 MFMA(u16x8 a, u16x8 b, f32x4 c){
    return __builtin_amdgcn_mfma_f32_16x16x32_bf16(
        __builtin_bit_cast(b16x8, a), __builtin_bit_cast(b16x8, b), c, 0, 0, 0);
}

// ---------------- fp32 -> bf16 convert (vectorized, 8 elems/thread) ----------------
__global__ __launch_bounds__(256) void k_f32_to_bf16(const float* __restrict__ src,
                                                     u16* __restrict__ dst, int n8){
    int i = blockIdx.x * 256 + threadIdx.x;
    if (i >= n8) return;
    const f32x4* s = (const f32x4*)src;
    f32x4 a = s[2*i], b = s[2*i+1];
    u16x8 o;
    o[0]=f2b(a[0]); o[1]=f2b(a[1]); o[2]=f2b(a[2]); o[3]=f2b(a[3]);
    o[4]=f2b(b[0]); o[5]=f2b(b[1]); o[6]=f2b(b[2]); o[7]=f2b(b[3]);
    *(u16x8*)(dst + 8*i) = o;
}

// ---------------- pool x over 8x8 regions (fp32 exact path for routing) ----------------
__global__ __launch_bounds__(256) void k_pool_x(const float* __restrict__ x,
                                                float* __restrict__ xp){
    int blk = blockIdx.x;                 // b*49 + reg
    int b = blk / NREG, reg = blk % NREG;
    int rh = reg / NWIN, rw = reg % NWIN;
    int t = threadIdx.x;
    const float* base = x + ((size_t)b*PPI + (rh*8)*WWD + rw*8) * CCH;
    for (int c = t; c < CCH; c += 256){
        float s = 0.f;
        #pragma unroll
        for (int a = 0; a < 8; a++)
            #pragma unroll
            for (int w2 = 0; w2 < 8; w2++)
                s += base[(a*WWD + w2)*CCH + c];
        xp[(size_t)blk*CCH + c] = s * (1.0f/64.0f);
    }
}

// ---------------- pooled q/k projection (fp32): qkp[blk][0:512]=q, [512:1024]=k ----------------
__global__ __launch_bounds__(256) void k_qk_pool(const float* __restrict__ xp,
                                                 const float* __restrict__ qkv_w,
                                                 const float* __restrict__ qkv_b,
                                                 float* __restrict__ qkp){
    int blk = blockIdx.x;                 // 392
    int t = threadIdx.x;
    int wave = t >> 6, lane = t & 63;
    const float* xr = xp + (size_t)blk*CCH;
    float xv[8];
    #pragma unroll
    for (int i = 0; i < 8; i++) xv[i] = xr[lane + 64*i];
    for (int oi = 0; oi < 256; oi++){
        int o = wave*256 + oi;            // 0..1023 -> qkv_w rows 0..1023 (q then k)
        const float* wr = qkv_w + (size_t)o*CCH;
        float p = 0.f;
        #pragma unroll
        for (int i = 0; i < 8; i++) p += xv[i] * wr[lane + 64*i];
        #pragma unroll
        for (int msk = 32; msk >= 1; msk >>= 1) p += __shfl_xor(p, msk, 64);
        if (lane == 0) qkp[(size_t)blk*1024 + o] = p + qkv_b[o];
    }
}

// ---------------- a_r scores + top-4 (fp32, stable tie-break = lowest index) ----------------
__global__ __launch_bounds__(64) void k_route(const float* __restrict__ qkp,
                                              int* __restrict__ idx){
    int blk = blockIdx.x;                 // b*49 + qreg
    int b = blk / NREG;
    int lane = threadIdx.x;
    __shared__ float sc[NREG];
    const float* qr = qkp + (size_t)blk*1024;
    float qv[8];
    #pragma unroll
    for (int i = 0; i < 8; i++) qv[i] = qr[lane + 64*i];
    for (int j = 0; j < NREG; j++){
        const float* kr = qkp + ((size_t)(b*NREG + j)*1024 + 512);
        float p = 0.f;
        #pragma unroll
        for (int i = 0; i < 8; i++) p += qv[i] * kr[lane + 64*i];
        #pragma unroll
        for (int msk = 32; msk >= 1; msk >>= 1) p += __shfl_xor(p, msk, 64);
        if (lane == 0) sc[j] = p;
    }
    __syncthreads();
    if (lane == 0){
        #pragma unroll
        for (int t = 0; t < TOPKK; t++){
            float best = -1e30f; int bj = 0;
            for (int j = 0; j < NREG; j++){
                if (sc[j] > best){ best = sc[j]; bj = j; }
            }
            idx[blk*TOPKK + t] = bj;
            sc[bj] = -1e30f;
        }
    }
}

// ---------------- QKV GEMM: [25088 x 512] x [1536 x 512]^T, scatter into seq layout ----------------
#define BM 128
#define BN 128
#define BK 64
__global__ __launch_bounds__(256) void k_gemm_qkv(const u16* __restrict__ xb,
                                                  const u16* __restrict__ wb,
                                                  const float* __restrict__ bias,
                                                  u16* __restrict__ q_s,
                                                  u16* __restrict__ k_s,
                                                  u16* __restrict__ v_s){
    __shared__ u16 As[BM*BK];
    __shared__ u16 Bs[BN*BK];
    int bx = blockIdx.x;
    int mt = bx / (OC/BN), nt = bx % (OC/BN);
    int pix0 = mt*BM, o0 = nt*BN;
    int t = threadIdx.x;
    int wid = t >> 6, lane = t & 63;
    int wm = wid >> 1, wn = wid & 1;
    int l15 = lane & 15, hi = lane >> 4;
    f32x4 acc[4][4];
    #pragma unroll
    for (int i = 0; i < 4; i++)
        #pragma unroll
        for (int j = 0; j < 4; j++) acc[i][j] = (f32x4){0.f,0.f,0.f,0.f};

    for (int ks = 0; ks < CCH/BK; ks++){
        int K0 = ks*BK;
        #pragma unroll
        for (int i = 0; i < 4; i++){
            int off = t*16 + i*4096;      // flat byte offset in 16KB tile
            int row = off >> 7;           // 128B per row (64 bf16)
            int kb  = off & 127;
            *(i32x4*)((char*)As + off) =
                *(const i32x4*)((const char*)xb + ((size_t)(pix0+row)*CCH + K0)*2 + kb);
            *(i32x4*)((char*)Bs + off) =
                *(const i32x4*)((const char*)wb + ((size_t)(o0 +row)*CCH + K0)*2 + kb);
        }
        __syncthreads();
        #pragma unroll
        for (int kk = 0; kk < 2; kk++){
            u16x8 af[4], bf[4];
            #pragma unroll
            for (int i = 0; i < 4; i++)
                af[i] = *(const u16x8*)&As[(wm*64 + i*16 + l15)*BK + kk*32 + hi*8];
            #pragma unroll
            for (int j = 0; j < 4; j++)
                bf[j] = *(const u16x8*)&Bs[(wn*64 + j*16 + l15)*BK + kk*32 + hi*8];
            #pragma unroll
            for (int i = 0; i < 4; i++)
                #pragma unroll
                for (int j = 0; j < 4; j++)
                    acc[i][j] = MFMA(af[i], bf[j], acc[i][j]);
        }
        __syncthreads();
    }
    // epilogue: scatter into q_s/k_s/v_s seq layout [b][head][reg][pix][d], add bias
    #pragma unroll
    for (int i = 0; i < 4; i++){
        int prow_base = pix0 + wm*64 + i*16 + 4*hi;
        #pragma unroll
        for (int j = 0; j < 4; j++){
            int o = o0 + wn*64 + j*16 + l15;
            int which = o >> 9;
            int c = o & 511;
            int m = c >> 6, d = c & 63;
            float bv = bias[o];
            u16* dst = (which == 0) ? q_s : (which == 1) ? k_s : v_s;
            #pragma unroll
            for (int r = 0; r < 4; r++){
                int pix = prow_base + r;
                int b  = pix / PPI;
                int pp = pix - b*PPI;
                int h  = pp / WWD, w2 = pp - h*WWD;
                int reg = (h >> 3)*NWIN + (w2 >> 3);
                int pr  = (h & 7)*8 + (w2 & 7);
                size_t oi = (((size_t)(b*NHEADS + m)*NREG + reg)*RSZ + pr)*HD + d;
                dst[oi] = f2b(acc[i][j][r] + bv);
            }
        }
    }
}

// ---------------- gathered window attention: block = (b, head, qreg) ----------------
__global__ __launch_bounds__(256) void k_attn(const u16* __restrict__ q_s,
                                              const u16* __restrict__ k_s,
                                              const u16* __restrict__ v_s,
                                              const int* __restrict__ idx,
                                              float* __restrict__ y){
    __shared__ u16 Ks[256*64];   // [key][d]; reused as P[64 rows][256 keys] after QK
    __shared__ u16 Vt[64*256];   // transposed: [d][key]
    int bid = blockIdx.x;
    int b  = bid / (NHEADS*NREG);
    int r2 = bid % (NHEADS*NREG);
    int m = r2 / NREG, qreg = r2 % NREG;
    int t = threadIdx.x, wid = t >> 6, lane = t & 63;
    int l15 = lane & 15, hi = lane >> 4;

    size_t hb = (size_t)(b*NHEADS + m)*NREG;
    int i4[4];
    #pragma unroll
    for (int j = 0; j < 4; j++) i4[j] = idx[(b*NREG + qreg)*TOPKK + j];

    // stage K (linear, coalesced: regions are contiguous 8KB blocks)
    #pragma unroll
    for (int i = 0; i < 8; i++){
        int off = t*16 + i*4096;
        int rsel = off >> 13;
        int within = off & 8191;
        const char* src = (const char*)(k_s + (hb + i4[rsel])*(RSZ*HD)) + within;
        *(i32x4*)((char*)Ks + off) = *(const i32x4*)src;
    }
    // stage V transposed: global coalesced read -> scalar LDS scatter
    #pragma unroll
    for (int i = 0; i < 8; i++){
        int off = t*16 + i*4096;
        int rsel = off >> 13;
        int within = off & 8191;
        int key = off >> 7;
        int d0  = (off & 127) >> 1;
        const char* src = (const char*)(v_s + (hb + i4[rsel])*(RSZ*HD)) + within;
        u16x8 v = *(const u16x8*)src;
        #pragma unroll
        for (int jj = 0; jj < 8; jj++) Vt[(d0+jj)*256 + key] = v[jj];
    }
    // q fragments straight from global (wave strip = rows wid*16..+16)
    const u16* qb = q_s + (hb + qreg)*(RSZ*HD);
    u16x8 aq[2];
    #pragma unroll
    for (int kk = 0; kk < 2; kk++)
        aq[kk] = *(const u16x8*)&qb[(wid*16 + l15)*HD + kk*32 + hi*8];
    __syncthreads();

    // QK^T: wave computes its 16-row strip x all 256 keys
    f32x4 s[16];
    #pragma unroll
    for (int fn = 0; fn < 16; fn++) s[fn] = (f32x4){0.f,0.f,0.f,0.f};
    #pragma unroll
    for (int kk = 0; kk < 2; kk++)
        #pragma unroll
        for (int fn = 0; fn < 16; fn++){
            u16x8 bf = *(const u16x8*)&Ks[(fn*16 + l15)*HD + kk*32 + hi*8];
            s[fn] = MFMA(aq[kk], bf, s[fn]);
        }
    // scale + in-register softmax (row r lives in lanes with same hi, across l15 x fn)
    #pragma unroll
    for (int fn = 0; fn < 16; fn++)
        #pragma unroll
        for (int rr = 0; rr < 4; rr++) s[fn][rr] *= SCALE_F;
    float inv[4];
    #pragma unroll
    for (int rr = 0; rr < 4; rr++){
        float v = s[0][rr];
        #pragma unroll
        for (int fn = 1; fn < 16; fn++) v = fmaxf(v, s[fn][rr]);
        #pragma unroll
        for (int msk = 1; msk < 16; msk <<= 1) v = fmaxf(v, __shfl_xor(v, msk, 64));
        float ss = 0.f;
        #pragma unroll
        for (int fn = 0; fn < 16; fn++){
            float e = __expf(s[fn][rr] - v);
            s[fn][rr] = e; ss += e;
        }
        #pragma unroll
        for (int msk = 1; msk < 16; msk <<= 1) ss += __shfl_xor(ss, msk, 64);
        inv[rr] = 1.0f / ss;
    }
    __syncthreads();               // all waves done reading Ks
    // write P (bf16) into Ks region: P[row][key]
    #pragma unroll
    for (int fn = 0; fn < 16; fn++)
        #pragma unroll
        for (int rr = 0; rr < 4; rr++)
            Ks[(wid*16 + 4*hi + rr)*256 + fn*16 + l15] = f2b(s[fn][rr]*inv[rr]);
    __syncthreads();
    // PV: strip rows x 64 d, K=256
    f32x4 o[4];
    #pragma unroll
    for (int j = 0; j < 4; j++) o[j] = (f32x4){0.f,0.f,0.f,0.f};
    #pragma unroll
    for (int ksx = 0; ksx < 8; ksx++){
        u16x8 pa = *(const u16x8*)&Ks[(wid*16 + l15)*256 + ksx*32 + hi*8];
        #pragma unroll
        for (int j = 0; j < 4; j++){
            u16x8 vb = *(const u16x8*)&Vt[(j*16 + l15)*256 + ksx*32 + hi*8];
            o[j] = MFMA(pa, vb, o[j]);
        }
    }
    // write out to NHWC y (fp32)
    int rh = qreg / NWIN, rw = qreg % NWIN;
    #pragma unroll
    for (int j = 0; j < 4; j++){
        int d = j*16 + l15;
        #pragma unroll
        for (int rr = 0; rr < 4; rr++){
            int prow = wid*16 + 4*hi + rr;
            int a = prow >> 3, bb2 = prow & 7;
            int h = rh*8 + a, w2 = rw*8 + bb2;
            y[((size_t)b*PPI + h*WWD + w2)*CCH + m*HD + d] = o[j][rr];
        }
    }
}

// ---------------- depthwise 3x3 LEPE from v_s (bf16), accumulate into y ----------------
__global__ __launch_bounds__(256) void k_lepe(const u16* __restrict__ v_s,
                                              const float* __restrict__ lw,
                                              const float* __restrict__ lb,
                                              float* __restrict__ y){
    int gid = blockIdx.x*256 + threadIdx.x;       // NPIX * 128
    if (gid >= NPIX*128) return;
    int p  = gid >> 7;
    int c0 = (gid & 127) * 4;
    int b  = p / PPI; int pp = p - b*PPI;
    int h  = pp / WWD, w2 = pp - h*WWD;
    int m = c0 >> 6, d0 = c0 & 63;
    size_t hb = (size_t)(b*NHEADS + m)*NREG;
    float a0 = lb[c0], a1 = lb[c0+1], a2 = lb[c0+2], a3 = lb[c0+3];
    #pragma unroll
    for (int kh = 0; kh < 3; kh++){
        int hh = h + kh - 1;
        if (hh < 0 || hh >= HH) continue;
        #pragma unroll
        for (int kw = 0; kw < 3; kw++){
            int ww = w2 + kw - 1;
            if (ww < 0 || ww >= WWD) continue;
            int reg = (hh >> 3)*NWIN + (ww >> 3);
            int pr  = (hh & 7)*8 + (ww & 7);
            const u16* src = v_s + ((hb + reg)*RSZ + pr)*HD + d0;
            u16x4 vv = *(const u16x4*)src;
            a0 += b2f(vv[0]) * lw[(c0  )*9 + kh*3 + kw];
            a1 += b2f(vv[1]) * lw[(c0+1)*9 + kh*3 + kw];
            a2 += b2f(vv[2]) * lw[(c0+2)*9 + kh*3 + kw];
            a3 += b2f(vv[3]) * lw[(c0+3)*9 + kh*3 + kw];
        }
    }
    f32x4* yp = (f32x4*)(y + (size_t)p*CCH + c0);
    f32x4 cur = *yp;
    cur[0] += a0; cur[1] += a1; cur[2] += a2; cur[3] += a3;
    *yp = cur;
}

// ---------------- output GEMM: [25088 x 512] x [512 x 512]^T -> fp32 NHWC ----------------
__global__ __launch_bounds__(256) void k_gemm_out(const u16* __restrict__ yb,
                                                  const u16* __restrict__ wb,
                                                  const float* __restrict__ bias,
                                                  float* __restrict__ out){
    __shared__ u16 As[BM*BK];
    __shared__ u16 Bs[BN*BK];
    int bx = blockIdx.x;
    int mt = bx >> 2, nt = bx & 3;
    int pix0 = mt*BM, o0 = nt*BN;
    int t = threadIdx.x;
    int wid = t >> 6, lane = t & 63;
    int wm = wid >> 1, wn = wid & 1;
    int l15 = lane & 15, hi = lane >> 4;
    f32x4 acc[4][4];
    #pragma unroll
    for (int i = 0; i < 4; i++)
        #pragma unroll
        for (int j = 0; j < 4; j++) acc[i][j] = (f32x4){0.f,0.f,0.f,0.f};

    for (int ks = 0; ks < CCH/BK; ks++){
        int K0 = ks*BK;
        #pragma unroll
        for (int i = 0; i < 4; i++){
            int off = t*16 + i*4096;
            int row = off >> 7;
            int kb  = off & 127;
            *(i32x4*)((char*)As + off) =
                *(const i32x4*)((const char*)yb + ((size_t)(pix0+row)*CCH + K0)*2 + kb);
            *(i32x4*)((char*)Bs + off) =
                *(const i32x4*)((const char*)wb + ((size_t)(o0 +row)*CCH + K0)*2 + kb);
        }
        __syncthreads();
        #pragma unroll
        for (int kk = 0; kk < 2; kk++){
            u16x8 af[4], bf[4];
            #pragma unroll
            for (int i = 0; i < 4; i++)
                af[i] = *(const u16x8*)&As[(wm*64 + i*16 + l15)*BK + kk*32 + hi*8];
            #pragma unroll
            for (int j = 0; j < 4; j++)
                bf[j] = *(const u16x8*)&Bs[(wn*64 + j*16 + l15)*BK + kk*32 + hi*8];
            #pragma unroll
            for (int i = 0; i < 4; i++)
                #pragma unroll
                for (int j = 0; j < 4; j++)
                    acc[i][j] = MFMA(af[i], bf[j], acc[i][j]);
        }
        __syncthreads();
    }
    #pragma unroll
    for (int i = 0; i < 4; i++){
        #pragma unroll
        for (int j = 0; j < 4; j++){
            int o = o0 + wn*64 + j*16 + l15;
            float bv = bias[o];
            #pragma unroll
            for (int r = 0; r < 4; r++){
                int pix = pix0 + wm*64 + i*16 + 4*hi + r;
                out[(size_t)pix*CCH + o] = acc[i][j][r] + bv;
            }
        }
    }
}

// ---------------- launch ----------------
extern "C" void kernel_launch(void* const* d_in, const int* in_sizes, int n_in,
                              void* d_out, int out_size, void* d_ws, size_t ws_size,
                              hipStream_t stream){
    const float* x      = (const float*)d_in[0];
    const float* qkv_w  = (const float*)d_in[1];
    const float* qkv_b  = (const float*)d_in[2];
    const float* lepe_w = (const float*)d_in[3];
    const float* lepe_b = (const float*)d_in[4];
    const float* out_w  = (const float*)d_in[5];
    const float* out_b  = (const float*)d_in[6];

    char* w = (char*)d_ws;
    u16*   xb   = (u16*)(w + 0);            // 25,690,112
    u16*   wqkv = (u16*)(w + 25690112);     //  1,572,864
    u16*   wout = (u16*)(w + 27262976);     //    524,288
    u16*   q_s  = (u16*)(w + 27787264);     // 25,690,112
    u16*   k_s  = (u16*)(w + 53477376);     // 25,690,112
    u16*   v_s  = (u16*)(w + 79167488);     // 25,690,112
    float* xp   = (float*)(w + 104857600);  //    802,816
    float* qkp  = (float*)(w + 105660416);  //  1,605,632
    int*   idx  = (int*)(w + 107266048);    //      6,272
    float* y    = (float*)(w + 107272320);  // 51,380,224
    u16*   yb   = (u16*)(w + 158652544);    // 25,690,112  (total 184,342,656)

    k_f32_to_bf16<<<dim3(6272), dim3(256), 0, stream>>>(x, xb, NPIX*CCH/8);
    k_f32_to_bf16<<<dim3(384),  dim3(256), 0, stream>>>(qkv_w, wqkv, OC*CCH/8);
    k_f32_to_bf16<<<dim3(128),  dim3(256), 0, stream>>>(out_w, wout, CCH*CCH/8);
    k_pool_x<<<dim3(BB*NREG), dim3(256), 0, stream>>>(x, xp);
    k_qk_pool<<<dim3(BB*NREG), dim3(256), 0, stream>>>(xp, qkv_w, qkv_b, qkp);
    k_route<<<dim3(BB*NREG), dim3(64), 0, stream>>>(qkp, idx);
    k_gemm_qkv<<<dim3((NPIX/BM)*(OC/BN)), dim3(256), 0, stream>>>(xb, wqkv, qkv_b, q_s, k_s, v_s);
    k_attn<<<dim3(BB*NHEADS*NREG), dim3(256), 0, stream>>>(q_s, k_s, v_s, idx, y);
    k_lepe<<<dim3(NPIX*128/256), dim3(256), 0, stream>>>(v_s, lepe_w, lepe_b, y);
    k_f32_to_bf16<<<dim3(6272), dim3(256), 0, stream>>>(y, yb, NPIX*CCH/8);
    k_gemm_out<<<dim3((NPIX/BM)*(CCH/BN)), dim3(256), 0, stream>>>(yb, wout, out_b, (float*)d_out);
}

// Round 2
// 449.648 us; speedup vs baseline: 1.1537x; 1.1537x over previous
//
#include <hip/hip_runtime.h>
#include <stdint.h>

#define BB      8
#define HH      56
#define WWD     56
#define CCH     512
#define NHEADS  8
#define HD      64
#define NWIN    7
#define NREG    49
#define RSZ     64
#define TOPKK   4
#define PPI     (HH*WWD)        // 3136
#define NPIX    (BB*PPI)        // 25088
#define OC      (3*CCH)         // 1536
#define SCALE_F 0.04419417382415922f

typedef unsigned short u16;
typedef u16   u16x8 __attribute__((ext_vector_type(8)));
typedef u16   u16x4 __attribute__((ext_vector_type(4)));
typedef __bf16 b16x8 __attribute__((ext_vector_type(8)));
typedef float f32x4 __attribute__((ext_vector_type(4)));
typedef int   i32x4 __attribute__((ext_vector_type(4)));

__device__ __forceinline__ u16 f2b(float f){
    unsigned u = __builtin_bit_cast(unsigned, f);
    return (u16)((u + 0x7fffu + ((u >> 16) & 1u)) >> 16);   // RNE
}
__device__ __forceinline__ float b2f(u16 h){
    return __builtin_bit_cast(float, (unsigned)h << 16);
}
__device__ __forceinline__ f32x4 MFMA(u16x8 a, u16x8 b, f32x4 c){
    return __builtin_amdgcn_mfma_f32_16x16x32_bf16(
        __builtin_bit_cast(b16x8, a), __builtin_bit_cast(b16x8, b), c, 0, 0, 0);
}

// ---------------- fp32 -> bf16 convert (vectorized, 8 elems/thread) ----------------
__global__ __launch_bounds__(256) void k_f32_to_bf16(const float* __restrict__ src,
                                                     u16* __restrict__ dst, int n8){
    int i = blockIdx.x * 256 + threadIdx.x;
    if (i >= n8) return;
    const f32x4* s = (const f32x4*)src;
    f32x4 a = s[2*i], b = s[2*i+1];
    u16x8 o;
    o[0]=f2b(a[0]); o[1]=f2b(a[1]); o[2]=f2b(a[2]); o[3]=f2b(a[3]);
    o[4]=f2b(b[0]); o[5]=f2b(b[1]); o[6]=f2b(b[2]); o[7]=f2b(b[3]);
    *(u16x8*)(dst + 8*i) = o;
}

// ---------------- pool x over 8x8 regions (fp32 exact path for routing) ----------------
__global__ __launch_bounds__(256) void k_pool_x(const float* __restrict__ x,
                                                float* __restrict__ xp){
    int blk = blockIdx.x;                 // b*49 + reg
    int b = blk / NREG, reg = blk % NREG;
    int rh = reg / NWIN, rw = reg % NWIN;
    int t = threadIdx.x;
    const float* base = x + ((size_t)b*PPI + (rh*8)*WWD + rw*8) * CCH;
    for (int c = t; c < CCH; c += 256){
        float s = 0.f;
        #pragma unroll
        for (int a = 0; a < 8; a++)
            #pragma unroll
            for (int w2 = 0; w2 < 8; w2++)
                s += base[(a*WWD + w2)*CCH + c];
        xp[(size_t)blk*CCH + c] = s * (1.0f/64.0f);
    }
}

// ---------------- pooled q/k projection as fp32 tiled GEMM ----------------
// C[392 x 1024] = XP[392 x 512] * qkv_w[0:1024][512]^T + bias
#define QP_BM 64
#define QP_BN 64
#define QP_BK 32
__global__ __launch_bounds__(256) void k_qk_pool(const float* __restrict__ xp,
                                                 const float* __restrict__ qkv_w,
                                                 const float* __restrict__ qkv_b,
                                                 float* __restrict__ qkp){
    __shared__ float Xs[QP_BK][QP_BM+1];
    __shared__ float Ws[QP_BK][QP_BN+1];
    int bx = blockIdx.x;                  // 7 row-tiles x 16 col-tiles = 112
    int mt = bx >> 4, nt = bx & 15;
    int row0 = mt*QP_BM, o0 = nt*QP_BN;
    int t = threadIdx.x;
    int tx = t & 15, ty = t >> 4;
    float acc[4][4];
    #pragma unroll
    for (int i = 0; i < 4; i++)
        #pragma unroll
        for (int j = 0; j < 4; j++) acc[i][j] = 0.f;

    for (int ks = 0; ks < CCH/QP_BK; ks++){
        int k0 = ks*QP_BK;
        #pragma unroll
        for (int i = 0; i < 8; i++){
            int idx = t + 256*i;          // 2048 elements per tile
            int row = idx >> 5, col = idx & 31;
            int gr = row0 + row;
            Xs[col][row] = (gr < BB*NREG) ? xp[(size_t)gr*CCH + k0 + col] : 0.f;
            Ws[col][row] = qkv_w[(size_t)(o0 + row)*CCH + k0 + col];
        }
        __syncthreads();
        #pragma unroll
        for (int kk = 0; kk < QP_BK; kk++){
            float a[4], bvv[4];
            #pragma unroll
            for (int i = 0; i < 4; i++) a[i] = Xs[kk][ty*4 + i];
            #pragma unroll
            for (int j = 0; j < 4; j++) bvv[j] = Ws[kk][tx*4 + j];
            #pragma unroll
            for (int i = 0; i < 4; i++)
                #pragma unroll
                for (int j = 0; j < 4; j++)
                    acc[i][j] += a[i] * bvv[j];
        }
        __syncthreads();
    }
    #pragma unroll
    for (int i = 0; i < 4; i++){
        int r = row0 + ty*4 + i;
        if (r >= BB*NREG) continue;
        #pragma unroll
        for (int j = 0; j < 4; j++){
            int o = o0 + tx*4 + j;
            qkp[(size_t)r*1024 + o] = acc[i][j] + qkv_b[o];
        }
    }
}

// ---------------- a_r scores + top-4 (fp32, stable tie-break = lowest index) ----------------
__global__ __launch_bounds__(64) void k_route(const float* __restrict__ qkp,
                                              int* __restrict__ idx){
    int blk = blockIdx.x;                 // b*49 + qreg
    int b = blk / NREG;
    int lane = threadIdx.x;
    __shared__ float sc[NREG];
    const float* qr = qkp + (size_t)blk*1024;
    float qv[8];
    #pragma unroll
    for (int i = 0; i < 8; i++) qv[i] = qr[lane + 64*i];
    for (int j = 0; j < NREG; j++){
        const float* kr = qkp + ((size_t)(b*NREG + j)*1024 + 512);
        float p = 0.f;
        #pragma unroll
        for (int i = 0; i < 8; i++) p += qv[i] * kr[lane + 64*i];
        #pragma unroll
        for (int msk = 32; msk >= 1; msk >>= 1) p += __shfl_xor(p, msk, 64);
        if (lane == 0) sc[j] = p;
    }
    __syncthreads();
    if (lane == 0){
        #pragma unroll
        for (int t = 0; t < TOPKK; t++){
            float best = -1e30f; int bj = 0;
            for (int j = 0; j < NREG; j++){
                if (sc[j] > best){ best = sc[j]; bj = j; }
            }
            idx[blk*TOPKK + t] = bj;
            sc[bj] = -1e30f;
        }
    }
}

// ---------------- QKV GEMM: [25088 x 512] x [1536 x 512]^T, scatter into seq layout ----------------
#define BM 128
#define BN 128
#define BK 64
__global__ __launch_bounds__(256) void k_gemm_qkv(const u16* __restrict__ xb,
                                                  const u16* __restrict__ wb,
                                                  const float* __restrict__ bias,
                                                  u16* __restrict__ q_s,
                                                  u16* __restrict__ k_s,
                                                  u16* __restrict__ v_s){
    __shared__ u16 As[BM*BK];
    __shared__ u16 Bs[BN*BK];
    int bx = blockIdx.x;
    int mt = bx / (OC/BN), nt = bx % (OC/BN);
    int pix0 = mt*BM, o0 = nt*BN;
    int t = threadIdx.x;
    int wid = t >> 6, lane = t & 63;
    int wm = wid >> 1, wn = wid & 1;
    int l15 = lane & 15, hi = lane >> 4;
    f32x4 acc[4][4];
    #pragma unroll
    for (int i = 0; i < 4; i++)
        #pragma unroll
        for (int j = 0; j < 4; j++) acc[i][j] = (f32x4){0.f,0.f,0.f,0.f};

    for (int ks = 0; ks < CCH/BK; ks++){
        int K0 = ks*BK;
        #pragma unroll
        for (int i = 0; i < 4; i++){
            int off = t*16 + i*4096;      // flat byte offset in 16KB tile
            int row = off >> 7;           // 128B per row (64 bf16)
            int kb  = off & 127;
            *(i32x4*)((char*)As + off) =
                *(const i32x4*)((const char*)xb + ((size_t)(pix0+row)*CCH + K0)*2 + kb);
            *(i32x4*)((char*)Bs + off) =
                *(const i32x4*)((const char*)wb + ((size_t)(o0 +row)*CCH + K0)*2 + kb);
        }
        __syncthreads();
        #pragma unroll
        for (int kk = 0; kk < 2; kk++){
            u16x8 af[4], bf[4];
            #pragma unroll
            for (int i = 0; i < 4; i++)
                af[i] = *(const u16x8*)&As[(wm*64 + i*16 + l15)*BK + kk*32 + hi*8];
            #pragma unroll
            for (int j = 0; j < 4; j++)
                bf[j] = *(const u16x8*)&Bs[(wn*64 + j*16 + l15)*BK + kk*32 + hi*8];
            #pragma unroll
            for (int i = 0; i < 4; i++)
                #pragma unroll
                for (int j = 0; j < 4; j++)
                    acc[i][j] = MFMA(af[i], bf[j], acc[i][j]);
        }
        __syncthreads();
    }
    // epilogue: scatter into q_s/k_s/v_s seq layout [b][head][reg][pix][d], add bias
    #pragma unroll
    for (int i = 0; i < 4; i++){
        int prow_base = pix0 + wm*64 + i*16 + 4*hi;
        #pragma unroll
        for (int j = 0; j < 4; j++){
            int o = o0 + wn*64 + j*16 + l15;
            int which = o >> 9;
            int c = o & 511;
            int m = c >> 6, d = c & 63;
            float bv = bias[o];
            u16* dst = (which == 0) ? q_s : (which == 1) ? k_s : v_s;
            #pragma unroll
            for (int r = 0; r < 4; r++){
                int pix = prow_base + r;
                int b  = pix / PPI;
                int pp = pix - b*PPI;
                int h  = pp / WWD, w2 = pp - h*WWD;
                int reg = (h >> 3)*NWIN + (w2 >> 3);
                int pr  = (h & 7)*8 + (w2 & 7);
                size_t oi = (((size_t)(b*NHEADS + m)*NREG + reg)*RSZ + pr)*HD + d;
                dst[oi] = f2b(acc[i][j][r] + bv);
            }
        }
    }
}

// ---------------- gathered window attention: block = (b, head, qreg) ----------------
__global__ __launch_bounds__(256) void k_attn(const u16* __restrict__ q_s,
                                              const u16* __restrict__ k_s,
                                              const u16* __restrict__ v_s,
                                              const int* __restrict__ idx,
                                              float* __restrict__ y){
    __shared__ u16 Ks[256*64];   // [key][d]; reused as P[64 rows][256 keys] after QK
    __shared__ u16 Vt[64*256];   // transposed: [d][key]
    int bid = blockIdx.x;
    int b  = bid / (NHEADS*NREG);
    int r2 = bid % (NHEADS*NREG);
    int m = r2 / NREG, qreg = r2 % NREG;
    int t = threadIdx.x, wid = t >> 6, lane = t & 63;
    int l15 = lane & 15, hi = lane >> 4;

    size_t hb = (size_t)(b*NHEADS + m)*NREG;
    int i4[4];
    #pragma unroll
    for (int j = 0; j < 4; j++) i4[j] = idx[(b*NREG + qreg)*TOPKK + j];

    // stage K (linear, coalesced: regions are contiguous 8KB blocks)
    #pragma unroll
    for (int i = 0; i < 8; i++){
        int off = t*16 + i*4096;
        int rsel = off >> 13;
        int within = off & 8191;
        const char* src = (const char*)(k_s + (hb + i4[rsel])*(RSZ*HD)) + within;
        *(i32x4*)((char*)Ks + off) = *(const i32x4*)src;
    }
    // stage V transposed: global coalesced read -> scalar LDS scatter
    #pragma unroll
    for (int i = 0; i < 8; i++){
        int off = t*16 + i*4096;
        int rsel = off >> 13;
        int within = off & 8191;
        int key = off >> 7;
        int d0  = (off & 127) >> 1;
        const char* src = (const char*)(v_s + (hb + i4[rsel])*(RSZ*HD)) + within;
        u16x8 v = *(const u16x8*)src;
        #pragma unroll
        for (int jj = 0; jj < 8; jj++) Vt[(d0+jj)*256 + key] = v[jj];
    }
    // q fragments straight from global (wave strip = rows wid*16..+16)
    const u16* qb = q_s + (hb + qreg)*(RSZ*HD);
    u16x8 aq[2];
    #pragma unroll
    for (int kk = 0; kk < 2; kk++)
        aq[kk] = *(const u16x8*)&qb[(wid*16 + l15)*HD + kk*32 + hi*8];
    __syncthreads();

    // QK^T: wave computes its 16-row strip x all 256 keys
    f32x4 s[16];
    #pragma unroll
    for (int fn = 0; fn < 16; fn++) s[fn] = (f32x4){0.f,0.f,0.f,0.f};
    #pragma unroll
    for (int kk = 0; kk < 2; kk++)
        #pragma unroll
        for (int fn = 0; fn < 16; fn++){
            u16x8 bf = *(const u16x8*)&Ks[(fn*16 + l15)*HD + kk*32 + hi*8];
            s[fn] = MFMA(aq[kk], bf, s[fn]);
        }
    // scale + in-register softmax (row r lives in lanes with same hi, across l15 x fn)
    #pragma unroll
    for (int fn = 0; fn < 16; fn++)
        #pragma unroll
        for (int rr = 0; rr < 4; rr++) s[fn][rr] *= SCALE_F;
    float inv[4];
    #pragma unroll
    for (int rr = 0; rr < 4; rr++){
        float v = s[0][rr];
        #pragma unroll
        for (int fn = 1; fn < 16; fn++) v = fmaxf(v, s[fn][rr]);
        #pragma unroll
        for (int msk = 1; msk < 16; msk <<= 1) v = fmaxf(v, __shfl_xor(v, msk, 64));
        float ss = 0.f;
        #pragma unroll
        for (int fn = 0; fn < 16; fn++){
            float e = __expf(s[fn][rr] - v);
            s[fn][rr] = e; ss += e;
        }
        #pragma unroll
        for (int msk = 1; msk < 16; msk <<= 1) ss += __shfl_xor(ss, msk, 64);
        inv[rr] = 1.0f / ss;
    }
    __syncthreads();               // all waves done reading Ks
    // write P (bf16) into Ks region: P[row][key]
    #pragma unroll
    for (int fn = 0; fn < 16; fn++)
        #pragma unroll
        for (int rr = 0; rr < 4; rr++)
            Ks[(wid*16 + 4*hi + rr)*256 + fn*16 + l15] = f2b(s[fn][rr]*inv[rr]);
    __syncthreads();
    // PV: strip rows x 64 d, K=256
    f32x4 o[4];
    #pragma unroll
    for (int j = 0; j < 4; j++) o[j] = (f32x4){0.f,0.f,0.f,0.f};
    #pragma unroll
    for (int ksx = 0; ksx < 8; ksx++){
        u16x8 pa = *(const u16x8*)&Ks[(wid*16 + l15)*256 + ksx*32 + hi*8];
        #pragma unroll
        for (int j = 0; j < 4; j++){
            u16x8 vb = *(const u16x8*)&Vt[(j*16 + l15)*256 + ksx*32 + hi*8];
            o[j] = MFMA(pa, vb, o[j]);
        }
    }
    // write out to NHWC y (fp32)
    int rh = qreg / NWIN, rw = qreg % NWIN;
    #pragma unroll
    for (int j = 0; j < 4; j++){
        int d = j*16 + l15;
        #pragma unroll
        for (int rr = 0; rr < 4; rr++){
            int prow = wid*16 + 4*hi + rr;
            int a = prow >> 3, bb2 = prow & 7;
            int h = rh*8 + a, w2 = rw*8 + bb2;
            y[((size_t)b*PPI + h*WWD + w2)*CCH + m*HD + d] = o[j][rr];
        }
    }
}

// ---------------- depthwise 3x3 LEPE from v_s (bf16), accumulate into y ----------------
__global__ __launch_bounds__(256) void k_lepe(const u16* __restrict__ v_s,
                                              const float* __restrict__ lw,
                                              const float* __restrict__ lb,
                                              float* __restrict__ y){
    int gid = blockIdx.x*256 + threadIdx.x;       // NPIX * 128
    if (gid >= NPIX*128) return;
    int p  = gid >> 7;
    int c0 = (gid & 127) * 4;
    int b  = p / PPI; int pp = p - b*PPI;
    int h  = pp / WWD, w2 = pp - h*WWD;
    int m = c0 >> 6, d0 = c0 & 63;
    size_t hb = (size_t)(b*NHEADS + m)*NREG;
    float a0 = lb[c0], a1 = lb[c0+1], a2 = lb[c0+2], a3 = lb[c0+3];
    #pragma unroll
    for (int kh = 0; kh < 3; kh++){
        int hh = h + kh - 1;
        if (hh < 0 || hh >= HH) continue;
        #pragma unroll
        for (int kw = 0; kw < 3; kw++){
            int ww = w2 + kw - 1;
            if (ww < 0 || ww >= WWD) continue;
            int reg = (hh >> 3)*NWIN + (ww >> 3);
            int pr  = (hh & 7)*8 + (ww & 7);
            const u16* src = v_s + ((hb + reg)*RSZ + pr)*HD + d0;
            u16x4 vv = *(const u16x4*)src;
            a0 += b2f(vv[0]) * lw[(c0  )*9 + kh*3 + kw];
            a1 += b2f(vv[1]) * lw[(c0+1)*9 + kh*3 + kw];
            a2 += b2f(vv[2]) * lw[(c0+2)*9 + kh*3 + kw];
            a3 += b2f(vv[3]) * lw[(c0+3)*9 + kh*3 + kw];
        }
    }
    f32x4* yp = (f32x4*)(y + (size_t)p*CCH + c0);
    f32x4 cur = *yp;
    cur[0] += a0; cur[1] += a1; cur[2] += a2; cur[3] += a3;
    *yp = cur;
}

// ---------------- output GEMM: [25088 x 512] x [512 x 512]^T -> fp32 NHWC ----------------
__global__ __launch_bounds__(256) void k_gemm_out(const u16* __restrict__ yb,
                                                  const u16* __restrict__ wb,
                                                  const float* __restrict__ bias,
                                                  float* __restrict__ out){
    __shared__ u16 As[BM*BK];
    __shared__ u16 Bs[BN*BK];
    int bx = blockIdx.x;
    int mt = bx >> 2, nt = bx & 3;
    int pix0 = mt*BM, o0 = nt*BN;
    int t = threadIdx.x;
    int wid = t >> 6, lane = t & 63;
    int wm = wid >> 1, wn = wid & 1;
    int l15 = lane & 15, hi = lane >> 4;
    f32x4 acc[4][4];
    #pragma unroll
    for (int i = 0; i < 4; i++)
        #pragma unroll
        for (int j = 0; j < 4; j++) acc[i][j] = (f32x4){0.f,0.f,0.f,0.f};

    for (int ks = 0; ks < CCH/BK; ks++){
        int K0 = ks*BK;
        #pragma unroll
        for (int i = 0; i < 4; i++){
            int off = t*16 + i*4096;
            int row = off >> 7;
            int kb  = off & 127;
            *(i32x4*)((char*)As + off) =
                *(const i32x4*)((const char*)yb + ((size_t)(pix0+row)*CCH + K0)*2 + kb);
            *(i32x4*)((char*)Bs + off) =
                *(const i32x4*)((const char*)wb + ((size_t)(o0 +row)*CCH + K0)*2 + kb);
        }
        __syncthreads();
        #pragma unroll
        for (int kk = 0; kk < 2; kk++){
            u16x8 af[4], bf[4];
            #pragma unroll
            for (int i = 0; i < 4; i++)
                af[i] = *(const u16x8*)&As[(wm*64 + i*16 + l15)*BK + kk*32 + hi*8];
            #pragma unroll
            for (int j = 0; j < 4; j++)
                bf[j] = *(const u16x8*)&Bs[(wn*64 + j*16 + l15)*BK + kk*32 + hi*8];
            #pragma unroll
            for (int i = 0; i < 4; i++)
                #pragma unroll
                for (int j = 0; j < 4; j++)
                    acc[i][j] = MFMA(af[i], bf[j], acc[i][j]);
        }
        __syncthreads();
    }
    #pragma unroll
    for (int i = 0; i < 4; i++){
        #pragma unroll
        for (int j = 0; j < 4; j++){
            int o = o0 + wn*64 + j*16 + l15;
            float bv = bias[o];
            #pragma unroll
            for (int r = 0; r < 4; r++){
                int pix = pix0 + wm*64 + i*16 + 4*hi + r;
                out[(size_t)pix*CCH + o] = acc[i][j][r] + bv;
            }
        }
    }
}

// ---------------- launch ----------------
extern "C" void kernel_launch(void* const* d_in, const int* in_sizes, int n_in,
                              void* d_out, int out_size, void* d_ws, size_t ws_size,
                              hipStream_t stream){
    const float* x      = (const float*)d_in[0];
    const float* qkv_w  = (const float*)d_in[1];
    const float* qkv_b  = (const float*)d_in[2];
    const float* lepe_w = (const float*)d_in[3];
    const float* lepe_b = (const float*)d_in[4];
    const float* out_w  = (const float*)d_in[5];
    const float* out_b  = (const float*)d_in[6];

    char* w = (char*)d_ws;
    u16*   xb   = (u16*)(w + 0);            // 25,690,112
    u16*   wqkv = (u16*)(w + 25690112);     //  1,572,864
    u16*   wout = (u16*)(w + 27262976);     //    524,288
    u16*   q_s  = (u16*)(w + 27787264);     // 25,690,112
    u16*   k_s  = (u16*)(w + 53477376);     // 25,690,112
    u16*   v_s  = (u16*)(w + 79167488);     // 25,690,112
    float* xp   = (float*)(w + 104857600);  //    802,816
    float* qkp  = (float*)(w + 105660416);  //  1,605,632
    int*   idx  = (int*)(w + 107266048);    //      6,272
    float* y    = (float*)(w + 107272320);  // 51,380,224
    u16*   yb   = (u16*)(w + 158652544);    // 25,690,112  (total 184,342,656)

    k_f32_to_bf16<<<dim3(6272), dim3(256), 0, stream>>>(x, xb, NPIX*CCH/8);
    k_f32_to_bf16<<<dim3(384),  dim3(256), 0, stream>>>(qkv_w, wqkv, OC*CCH/8);
    k_f32_to_bf16<<<dim3(128),  dim3(256), 0, stream>>>(out_w, wout, CCH*CCH/8);
    k_pool_x<<<dim3(BB*NREG), dim3(256), 0, stream>>>(x, xp);
    k_qk_pool<<<dim3(112), dim3(256), 0, stream>>>(xp, qkv_w, qkv_b, qkp);
    k_route<<<dim3(BB*NREG), dim3(64), 0, stream>>>(qkp, idx);
    k_gemm_qkv<<<dim3((NPIX/BM)*(OC/BN)), dim3(256), 0, stream>>>(xb, wqkv, qkv_b, q_s, k_s, v_s);
    k_attn<<<dim3(BB*NHEADS*NREG), dim3(256), 0, stream>>>(q_s, k_s, v_s, idx, y);
    k_lepe<<<dim3(NPIX*128/256), dim3(256), 0, stream>>>(v_s, lepe_w, lepe_b, y);
    k_f32_to_bf16<<<dim3(6272), dim3(256), 0, stream>>>(y, yb, NPIX*CCH/8);
    k_gemm_out<<<dim3((NPIX/BM)*(CCH/BN)), dim3(256), 0, stream>>>(yb, wout, out_b, (float*)d_out);
}

// Round 3
// 340.009 us; speedup vs baseline: 1.5257x; 1.3225x over previous
//
#include <hip/hip_runtime.h>
#include <stdint.h>

#define BB      8
#define HH      56
#define WWD     56
#define CCH     512
#define NHEADS  8
#define HD      64
#define NWIN    7
#define NREG    49
#define RSZ     64
#define TOPKK   4
#define PPI     (HH*WWD)        // 3136
#define NPIX    (BB*PPI)        // 25088
#define OC      (3*CCH)         // 1536
#define SCALE_F 0.04419417382415922f

typedef unsigned short u16;
typedef u16   u16x8 __attribute__((ext_vector_type(8)));
typedef u16   u16x4 __attribute__((ext_vector_type(4)));
typedef __bf16 b16x8 __attribute__((ext_vector_type(8)));
typedef float f32x4 __attribute__((ext_vector_type(4)));
typedef int   i32x4 __attribute__((ext_vector_type(4)));

__device__ __forceinline__ u16 f2b(float f){
    unsigned u = __builtin_bit_cast(unsigned, f);
    return (u16)((u + 0x7fffu + ((u >> 16) & 1u)) >> 16);   // RNE
}
__device__ __forceinline__ float b2f(u16 h){
    return __builtin_bit_cast(float, (unsigned)h << 16);
}
__device__ __forceinline__ f32x4 MFMA(u16x8 a, u16x8 b, f32x4 c){
    return __builtin_amdgcn_mfma_f32_16x16x32_bf16(
        __builtin_bit_cast(b16x8, a), __builtin_bit_cast(b16x8, b), c, 0, 0, 0);
}

// ---------------- fp32 -> bf16 convert (vectorized, 8 elems/thread) ----------------
__global__ __launch_bounds__(256) void k_f32_to_bf16(const float* __restrict__ src,
                                                     u16* __restrict__ dst, int n8){
    int i = blockIdx.x * 256 + threadIdx.x;
    if (i >= n8) return;
    const f32x4* s = (const f32x4*)src;
    f32x4 a = s[2*i], b = s[2*i+1];
    u16x8 o;
    o[0]=f2b(a[0]); o[1]=f2b(a[1]); o[2]=f2b(a[2]); o[3]=f2b(a[3]);
    o[4]=f2b(b[0]); o[5]=f2b(b[1]); o[6]=f2b(b[2]); o[7]=f2b(b[3]);
    *(u16x8*)(dst + 8*i) = o;
}

// ---------------- pool x over 8x8 regions (fp32 exact path for routing) ----------------
__global__ __launch_bounds__(256) void k_pool_x(const float* __restrict__ x,
                                                float* __restrict__ xp){
    int blk = blockIdx.x;                 // b*49 + reg
    int b = blk / NREG, reg = blk % NREG;
    int rh = reg / NWIN, rw = reg % NWIN;
    int t = threadIdx.x;
    const float* base = x + ((size_t)b*PPI + (rh*8)*WWD + rw*8) * CCH;
    for (int c = t; c < CCH; c += 256){
        float s = 0.f;
        #pragma unroll
        for (int a = 0; a < 8; a++)
            #pragma unroll
            for (int w2 = 0; w2 < 8; w2++)
                s += base[(a*WWD + w2)*CCH + c];
        xp[(size_t)blk*CCH + c] = s * (1.0f/64.0f);
    }
}

// ---------------- pooled q/k projection as fp32 tiled GEMM ----------------
#define QP_BM 64
#define QP_BN 64
#define QP_BK 32
__global__ __launch_bounds__(256) void k_qk_pool(const float* __restrict__ xp,
                                                 const float* __restrict__ qkv_w,
                                                 const float* __restrict__ qkv_b,
                                                 float* __restrict__ qkp){
    __shared__ float Xs[QP_BK][QP_BM+1];
    __shared__ float Ws[QP_BK][QP_BN+1];
    int bx = blockIdx.x;                  // 7 row-tiles x 16 col-tiles = 112
    int mt = bx >> 4, nt = bx & 15;
    int row0 = mt*QP_BM, o0 = nt*QP_BN;
    int t = threadIdx.x;
    int tx = t & 15, ty = t >> 4;
    float acc[4][4];
    #pragma unroll
    for (int i = 0; i < 4; i++)
        #pragma unroll
        for (int j = 0; j < 4; j++) acc[i][j] = 0.f;

    for (int ks = 0; ks < CCH/QP_BK; ks++){
        int k0 = ks*QP_BK;
        #pragma unroll
        for (int i = 0; i < 8; i++){
            int idx = t + 256*i;          // 2048 elements per tile
            int row = idx >> 5, col = idx & 31;
            int gr = row0 + row;
            Xs[col][row] = (gr < BB*NREG) ? xp[(size_t)gr*CCH + k0 + col] : 0.f;
            Ws[col][row] = qkv_w[(size_t)(o0 + row)*CCH + k0 + col];
        }
        __syncthreads();
        #pragma unroll
        for (int kk = 0; kk < QP_BK; kk++){
            float a[4], bvv[4];
            #pragma unroll
            for (int i = 0; i < 4; i++) a[i] = Xs[kk][ty*4 + i];
            #pragma unroll
            for (int j = 0; j < 4; j++) bvv[j] = Ws[kk][tx*4 + j];
            #pragma unroll
            for (int i = 0; i < 4; i++)
                #pragma unroll
                for (int j = 0; j < 4; j++)
                    acc[i][j] += a[i] * bvv[j];
        }
        __syncthreads();
    }
    #pragma unroll
    for (int i = 0; i < 4; i++){
        int r = row0 + ty*4 + i;
        if (r >= BB*NREG) continue;
        #pragma unroll
        for (int j = 0; j < 4; j++){
            int o = o0 + tx*4 + j;
            qkp[(size_t)r*1024 + o] = acc[i][j] + qkv_b[o];
        }
    }
}

// ---------------- a_r scores + top-4 (fp32, stable tie-break = lowest index) ----------------
__global__ __launch_bounds__(64) void k_route(const float* __restrict__ qkp,
                                              int* __restrict__ idx){
    int blk = blockIdx.x;                 // b*49 + qreg
    int b = blk / NREG;
    int lane = threadIdx.x;
    __shared__ float sc[NREG];
    const float* qr = qkp + (size_t)blk*1024;
    float qv[8];
    #pragma unroll
    for (int i = 0; i < 8; i++) qv[i] = qr[lane + 64*i];
    for (int j = 0; j < NREG; j++){
        const float* kr = qkp + ((size_t)(b*NREG + j)*1024 + 512);
        float p = 0.f;
        #pragma unroll
        for (int i = 0; i < 8; i++) p += qv[i] * kr[lane + 64*i];
        #pragma unroll
        for (int msk = 32; msk >= 1; msk >>= 1) p += __shfl_xor(p, msk, 64);
        if (lane == 0) sc[j] = p;
    }
    __syncthreads();
    if (lane == 0){
        #pragma unroll
        for (int t = 0; t < TOPKK; t++){
            float best = -1e30f; int bj = 0;
            for (int j = 0; j < NREG; j++){
                if (sc[j] > best){ best = sc[j]; bj = j; }
            }
            idx[blk*TOPKK + t] = bj;
            sc[bj] = -1e30f;
        }
    }
}

// ---------------- QKV GEMM: [25088 x 512] x [1536 x 512]^T, scatter into seq layout ----------------
#define BM 128
#define BN 128
#define BK 64
__global__ __launch_bounds__(256) void k_gemm_qkv(const u16* __restrict__ xb,
                                                  const u16* __restrict__ wb,
                                                  const float* __restrict__ bias,
                                                  u16* __restrict__ q_s,
                                                  u16* __restrict__ k_s,
                                                  u16* __restrict__ v_s){
    __shared__ u16 As[BM*BK];
    __shared__ u16 Bs[BN*BK];
    int bx = blockIdx.x;
    int mt = bx / (OC/BN), nt = bx % (OC/BN);
    int pix0 = mt*BM, o0 = nt*BN;
    int t = threadIdx.x;
    int wid = t >> 6, lane = t & 63;
    int wm = wid >> 1, wn = wid & 1;
    int l15 = lane & 15, hi = lane >> 4;
    f32x4 acc[4][4];
    #pragma unroll
    for (int i = 0; i < 4; i++)
        #pragma unroll
        for (int j = 0; j < 4; j++) acc[i][j] = (f32x4){0.f,0.f,0.f,0.f};

    for (int ks = 0; ks < CCH/BK; ks++){
        int K0 = ks*BK;
        #pragma unroll
        for (int i = 0; i < 4; i++){
            int off = t*16 + i*4096;      // flat byte offset in 16KB tile
            int row = off >> 7;           // 128B per row (64 bf16)
            int kb  = off & 127;
            *(i32x4*)((char*)As + off) =
                *(const i32x4*)((const char*)xb + ((size_t)(pix0+row)*CCH + K0)*2 + kb);
            *(i32x4*)((char*)Bs + off) =
                *(const i32x4*)((const char*)wb + ((size_t)(o0 +row)*CCH + K0)*2 + kb);
        }
        __syncthreads();
        #pragma unroll
        for (int kk = 0; kk < 2; kk++){
            u16x8 af[4], bf[4];
            #pragma unroll
            for (int i = 0; i < 4; i++)
                af[i] = *(const u16x8*)&As[(wm*64 + i*16 + l15)*BK + kk*32 + hi*8];
            #pragma unroll
            for (int j = 0; j < 4; j++)
                bf[j] = *(const u16x8*)&Bs[(wn*64 + j*16 + l15)*BK + kk*32 + hi*8];
            #pragma unroll
            for (int i = 0; i < 4; i++)
                #pragma unroll
                for (int j = 0; j < 4; j++)
                    acc[i][j] = MFMA(af[i], bf[j], acc[i][j]);
        }
        __syncthreads();
    }
    // epilogue: scatter into q_s/k_s/v_s seq layout [b][head][reg][pix][d], add bias
    #pragma unroll
    for (int i = 0; i < 4; i++){
        int prow_base = pix0 + wm*64 + i*16 + 4*hi;
        #pragma unroll
        for (int j = 0; j < 4; j++){
            int o = o0 + wn*64 + j*16 + l15;
            int which = o >> 9;
            int c = o & 511;
            int m = c >> 6, d = c & 63;
            float bv = bias[o];
            u16* dst = (which == 0) ? q_s : (which == 1) ? k_s : v_s;
            #pragma unroll
            for (int r = 0; r < 4; r++){
                int pix = prow_base + r;
                int b  = pix / PPI;
                int pp = pix - b*PPI;
                int h  = pp / WWD, w2 = pp - h*WWD;
                int reg = (h >> 3)*NWIN + (w2 >> 3);
                int pr  = (h & 7)*8 + (w2 & 7);
                size_t oi = (((size_t)(b*NHEADS + m)*NREG + reg)*RSZ + pr)*HD + d;
                dst[oi] = f2b(acc[i][j][r] + bv);
            }
        }
    }
}

// ---------------- fused attention + LEPE: block = (b, head, qreg), writes bf16 yb ----------------
__global__ __launch_bounds__(256) void k_attn(const u16* __restrict__ q_s,
                                              const u16* __restrict__ k_s,
                                              const u16* __restrict__ v_s,
                                              const int* __restrict__ idx,
                                              const float* __restrict__ lw,
                                              const float* __restrict__ lb,
                                              u16* __restrict__ yb){
    __shared__ u16 Ks[256*64];   // [key][d]; reused as P[64 rows][256 keys] after QK
    __shared__ u16 Vt[64*256];   // transposed [d][key]; reused as lepe halo after PV
    __shared__ float Wl[64*9];   // lepe weights for this head
    __shared__ float Bl[64];     // lepe bias for this head
    int bid = blockIdx.x;
    int b  = bid / (NHEADS*NREG);
    int r2 = bid % (NHEADS*NREG);
    int m = r2 / NREG, qreg = r2 % NREG;
    int rh = qreg / NWIN, rw = qreg % NWIN;
    int t = threadIdx.x, wid = t >> 6, lane = t & 63;
    int l15 = lane & 15, hi = lane >> 4;

    size_t hb = (size_t)(b*NHEADS + m)*NREG;
    int i4[4];
    #pragma unroll
    for (int j = 0; j < 4; j++) i4[j] = idx[(b*NREG + qreg)*TOPKK + j];

    // issue lepe halo loads early (10x10 cells x 64 d, 8 d per chunk -> 800 chunks)
    u16x8 halo0 = (u16x8){0,0,0,0,0,0,0,0}, halo1 = halo0, halo2 = halo0, halo3 = halo0;
    #pragma unroll
    for (int i = 0; i < 4; i++){
        int c = t + 256*i;
        if (c < 800){
            int cell = c >> 3, part = c & 7;
            int hr = cell / 10, wc = cell % 10;
            int hh2 = rh*8 - 1 + hr, ww2 = rw*8 - 1 + wc;
            if (hh2 >= 0 && hh2 < HH && ww2 >= 0 && ww2 < WWD){
                int reg2 = (hh2 >> 3)*NWIN + (ww2 >> 3);
                int pr2  = (hh2 & 7)*8 + (ww2 & 7);
                u16x8 v8 = *(const u16x8*)&v_s[((hb + reg2)*RSZ + pr2)*HD + part*8];
                if (i == 0) halo0 = v8; else if (i == 1) halo1 = v8;
                else if (i == 2) halo2 = v8; else halo3 = v8;
            }
        }
    }
    // stage lepe weights/bias
    for (int i = t; i < 64*9; i += 256) Wl[i] = lw[(m*64 + i/9)*9 + (i%9)];
    if (t < 64) Bl[t] = lb[m*64 + t];

    // stage K (linear, coalesced: regions are contiguous 8KB blocks)
    #pragma unroll
    for (int i = 0; i < 8; i++){
        int off = t*16 + i*4096;
        int rsel = off >> 13;
        int within = off & 8191;
        const char* src = (const char*)(k_s + (hb + i4[rsel])*(RSZ*HD)) + within;
        *(i32x4*)((char*)Ks + off) = *(const i32x4*)src;
    }
    // stage V transposed: global coalesced read -> scalar LDS scatter
    #pragma unroll
    for (int i = 0; i < 8; i++){
        int off = t*16 + i*4096;
        int rsel = off >> 13;
        int within = off & 8191;
        int key = off >> 7;
        int d0  = (off & 127) >> 1;
        const char* src = (const char*)(v_s + (hb + i4[rsel])*(RSZ*HD)) + within;
        u16x8 v = *(const u16x8*)src;
        #pragma unroll
        for (int jj = 0; jj < 8; jj++) Vt[(d0+jj)*256 + key] = v[jj];
    }
    // q fragments straight from global (wave strip = rows wid*16..+16)
    const u16* qb = q_s + (hb + qreg)*(RSZ*HD);
    u16x8 aq[2];
    #pragma unroll
    for (int kk = 0; kk < 2; kk++)
        aq[kk] = *(const u16x8*)&qb[(wid*16 + l15)*HD + kk*32 + hi*8];
    __syncthreads();

    // QK^T: wave computes its 16-row strip x all 256 keys
    f32x4 s[16];
    #pragma unroll
    for (int fn = 0; fn < 16; fn++) s[fn] = (f32x4){0.f,0.f,0.f,0.f};
    #pragma unroll
    for (int kk = 0; kk < 2; kk++)
        #pragma unroll
        for (int fn = 0; fn < 16; fn++){
            u16x8 bf = *(const u16x8*)&Ks[(fn*16 + l15)*HD + kk*32 + hi*8];
            s[fn] = MFMA(aq[kk], bf, s[fn]);
        }
    // scale + in-register softmax (row r lives in lanes with same hi, across l15 x fn)
    #pragma unroll
    for (int fn = 0; fn < 16; fn++)
        #pragma unroll
        for (int rr = 0; rr < 4; rr++) s[fn][rr] *= SCALE_F;
    float inv[4];
    #pragma unroll
    for (int rr = 0; rr < 4; rr++){
        float v = s[0][rr];
        #pragma unroll
        for (int fn = 1; fn < 16; fn++) v = fmaxf(v, s[fn][rr]);
        #pragma unroll
        for (int msk = 1; msk < 16; msk <<= 1) v = fmaxf(v, __shfl_xor(v, msk, 64));
        float ss = 0.f;
        #pragma unroll
        for (int fn = 0; fn < 16; fn++){
            float e = __expf(s[fn][rr] - v);
            s[fn][rr] = e; ss += e;
        }
        #pragma unroll
        for (int msk = 1; msk < 16; msk <<= 1) ss += __shfl_xor(ss, msk, 64);
        inv[rr] = 1.0f / ss;
    }
    __syncthreads();               // all waves done reading Ks
    // write P (bf16) into Ks region: P[row][key]
    #pragma unroll
    for (int fn = 0; fn < 16; fn++)
        #pragma unroll
        for (int rr = 0; rr < 4; rr++)
            Ks[(wid*16 + 4*hi + rr)*256 + fn*16 + l15] = f2b(s[fn][rr]*inv[rr]);
    __syncthreads();
    // PV: strip rows x 64 d, K=256
    f32x4 o[4];
    #pragma unroll
    for (int j = 0; j < 4; j++) o[j] = (f32x4){0.f,0.f,0.f,0.f};
    #pragma unroll
    for (int ksx = 0; ksx < 8; ksx++){
        u16x8 pa = *(const u16x8*)&Ks[(wid*16 + l15)*256 + ksx*32 + hi*8];
        #pragma unroll
        for (int j = 0; j < 4; j++){
            u16x8 vb = *(const u16x8*)&Vt[(j*16 + l15)*256 + ksx*32 + hi*8];
            o[j] = MFMA(pa, vb, o[j]);
        }
    }
    __syncthreads();               // Vt no longer needed; reuse for halo
    // halo -> LDS, padded cell stride 72 u16 (144B: 16B-aligned, bank-disjoint groups)
    #pragma unroll
    for (int i = 0; i < 4; i++){
        int c = t + 256*i;
        if (c < 800){
            int cell = c >> 3, part = c & 7;
            u16x8 v8 = (i == 0) ? halo0 : (i == 1) ? halo1 : (i == 2) ? halo2 : halo3;
            *(u16x8*)&Vt[cell*72 + part*8] = v8;
        }
    }
    __syncthreads();
    // lepe + output: thread covers row a_row, cols col0..col0+3, channels j*16+l15
    int a_row = wid*2 + (hi >> 1);
    int col0  = (hi & 1)*4;
    #pragma unroll
    for (int j = 0; j < 4; j++){
        int d = j*16 + l15;
        float w9[9];
        #pragma unroll
        for (int tap = 0; tap < 9; tap++) w9[tap] = Wl[d*9 + tap];
        float bias = Bl[d];
        #pragma unroll
        for (int rr = 0; rr < 4; rr++){
            int col = col0 + rr;
            float acc = bias;
            #pragma unroll
            for (int kh = 0; kh < 3; kh++)
                #pragma unroll
                for (int kw = 0; kw < 3; kw++)
                    acc += b2f(Vt[((a_row + kh)*10 + (col + kw))*72 + d]) * w9[kh*3 + kw];
            float val = o[j][rr] + acc;
            int h = rh*8 + a_row, w2c = rw*8 + col;
            yb[((size_t)b*PPI + h*WWD + w2c)*CCH + m*HD + d] = f2b(val);
        }
    }
}

// ---------------- output GEMM: [25088 x 512] x [512 x 512]^T -> fp32 NHWC ----------------
__global__ __launch_bounds__(256) void k_gemm_out(const u16* __restrict__ yb,
                                                  const u16* __restrict__ wb,
                                                  const float* __restrict__ bias,
                                                  float* __restrict__ out){
    __shared__ u16 As[BM*BK];
    __shared__ u16 Bs[BN*BK];
    int bx = blockIdx.x;
    int mt = bx >> 2, nt = bx & 3;
    int pix0 = mt*BM, o0 = nt*BN;
    int t = threadIdx.x;
    int wid = t >> 6, lane = t & 63;
    int wm = wid >> 1, wn = wid & 1;
    int l15 = lane & 15, hi = lane >> 4;
    f32x4 acc[4][4];
    #pragma unroll
    for (int i = 0; i < 4; i++)
        #pragma unroll
        for (int j = 0; j < 4; j++) acc[i][j] = (f32x4){0.f,0.f,0.f,0.f};

    for (int ks = 0; ks < CCH/BK; ks++){
        int K0 = ks*BK;
        #pragma unroll
        for (int i = 0; i < 4; i++){
            int off = t*16 + i*4096;
            int row = off >> 7;
            int kb  = off & 127;
            *(i32x4*)((char*)As + off) =
                *(const i32x4*)((const char*)yb + ((size_t)(pix0+row)*CCH + K0)*2 + kb);
            *(i32x4*)((char*)Bs + off) =
                *(const i32x4*)((const char*)wb + ((size_t)(o0 +row)*CCH + K0)*2 + kb);
        }
        __syncthreads();
        #pragma unroll
        for (int kk = 0; kk < 2; kk++){
            u16x8 af[4], bf[4];
            #pragma unroll
            for (int i = 0; i < 4; i++)
                af[i] = *(const u16x8*)&As[(wm*64 + i*16 + l15)*BK + kk*32 + hi*8];
            #pragma unroll
            for (int j = 0; j < 4; j++)
                bf[j] = *(const u16x8*)&Bs[(wn*64 + j*16 + l15)*BK + kk*32 + hi*8];
            #pragma unroll
            for (int i = 0; i < 4; i++)
                #pragma unroll
                for (int j = 0; j < 4; j++)
                    acc[i][j] = MFMA(af[i], bf[j], acc[i][j]);
        }
        __syncthreads();
    }
    #pragma unroll
    for (int i = 0; i < 4; i++){
        #pragma unroll
        for (int j = 0; j < 4; j++){
            int o = o0 + wn*64 + j*16 + l15;
            float bv = bias[o];
            #pragma unroll
            for (int r = 0; r < 4; r++){
                int pix = pix0 + wm*64 + i*16 + 4*hi + r;
                out[(size_t)pix*CCH + o] = acc[i][j][r] + bv;
            }
        }
    }
}

// ---------------- launch ----------------
extern "C" void kernel_launch(void* const* d_in, const int* in_sizes, int n_in,
                              void* d_out, int out_size, void* d_ws, size_t ws_size,
                              hipStream_t stream){
    const float* x      = (const float*)d_in[0];
    const float* qkv_w  = (const float*)d_in[1];
    const float* qkv_b  = (const float*)d_in[2];
    const float* lepe_w = (const float*)d_in[3];
    const float* lepe_b = (const float*)d_in[4];
    const float* out_w  = (const float*)d_in[5];
    const float* out_b  = (const float*)d_in[6];

    char* w = (char*)d_ws;
    u16*   xb   = (u16*)(w + 0);            // 25,690,112
    u16*   wqkv = (u16*)(w + 25690112);     //  1,572,864
    u16*   wout = (u16*)(w + 27262976);     //    524,288
    u16*   q_s  = (u16*)(w + 27787264);     // 25,690,112
    u16*   k_s  = (u16*)(w + 53477376);     // 25,690,112
    u16*   v_s  = (u16*)(w + 79167488);     // 25,690,112
    float* xp   = (float*)(w + 104857600);  //    802,816
    float* qkp  = (float*)(w + 105660416);  //  1,605,632
    int*   idx  = (int*)(w + 107266048);    //      6,272
    u16*   yb   = (u16*)(w + 107272320);    // 25,690,112

    k_f32_to_bf16<<<dim3(6272), dim3(256), 0, stream>>>(x, xb, NPIX*CCH/8);
    k_f32_to_bf16<<<dim3(384),  dim3(256), 0, stream>>>(qkv_w, wqkv, OC*CCH/8);
    k_f32_to_bf16<<<dim3(128),  dim3(256), 0, stream>>>(out_w, wout, CCH*CCH/8);
    k_pool_x<<<dim3(BB*NREG), dim3(256), 0, stream>>>(x, xp);
    k_qk_pool<<<dim3(112), dim3(256), 0, stream>>>(xp, qkv_w, qkv_b, qkp);
    k_route<<<dim3(BB*NREG), dim3(64), 0, stream>>>(qkp, idx);
    k_gemm_qkv<<<dim3((NPIX/BM)*(OC/BN)), dim3(256), 0, stream>>>(xb, wqkv, qkv_b, q_s, k_s, v_s);
    k_attn<<<dim3(BB*NHEADS*NREG), dim3(256), 0, stream>>>(q_s, k_s, v_s, idx, lepe_w, lepe_b, yb);
    k_gemm_out<<<dim3((NPIX/BM)*(CCH/BN)), dim3(256), 0, stream>>>(yb, wout, out_b, (float*)d_out);
}

// Round 4
// 280.040 us; speedup vs baseline: 1.8525x; 1.2141x over previous
//
#include <hip/hip_runtime.h>
#include <stdint.h>

#define BB      8
#define HH      56
#define WWD     56
#define CCH     512
#define NHEADS  8
#define HD      64
#define NWIN    7
#define NREG    49
#define RSZ     64
#define TOPKK   4
#define PPI     (HH*WWD)        // 3136
#define NPIX    (BB*PPI)        // 25088
#define OC      (3*CCH)         // 1536
#define SCALE_F 0.04419417382415922f

typedef unsigned short u16;
typedef u16   u16x8 __attribute__((ext_vector_type(8)));
typedef u16   u16x4 __attribute__((ext_vector_type(4)));
typedef __bf16 b16x8 __attribute__((ext_vector_type(8)));
typedef float f32x4 __attribute__((ext_vector_type(4)));
typedef int   i32x4 __attribute__((ext_vector_type(4)));

__device__ __forceinline__ u16 f2b(float f){
    unsigned u = __builtin_bit_cast(unsigned, f);
    return (u16)((u + 0x7fffu + ((u >> 16) & 1u)) >> 16);   // RNE
}
__device__ __forceinline__ float b2f(u16 h){
    return __builtin_bit_cast(float, (unsigned)h << 16);
}
__device__ __forceinline__ f32x4 MFMA(u16x8 a, u16x8 b, f32x4 c){
    return __builtin_amdgcn_mfma_f32_16x16x32_bf16(
        __builtin_bit_cast(b16x8, a), __builtin_bit_cast(b16x8, b), c, 0, 0, 0);
}
// XOR-swizzle term (u16-index units, 16B granular). Spreads both l15-varying
// read rows (bits 0-2) and stride-8 scatter-write rows (bits 3-5).
__device__ __forceinline__ int sw8(int row){ return ((row ^ (row >> 3)) & 7) << 3; }

// async global->LDS 16B (CK-style addrspace cast via integer round-trip)
__device__ __forceinline__ void gld16(const void* g, void* l){
    auto gp = (const __attribute__((address_space(1))) unsigned int*)(unsigned long long)(g);
    auto lp = (__attribute__((address_space(3))) unsigned int*)(unsigned int)(unsigned long long)(l);
    __builtin_amdgcn_global_load_lds(gp, lp, 16, 0, 0);
}

// ---------------- fp32 -> bf16 convert (vectorized, 8 elems/thread) ----------------
__global__ __launch_bounds__(256) void k_f32_to_bf16(const float* __restrict__ src,
                                                     u16* __restrict__ dst, int n8){
    int i = blockIdx.x * 256 + threadIdx.x;
    if (i >= n8) return;
    const f32x4* s = (const f32x4*)src;
    f32x4 a = s[2*i], b = s[2*i+1];
    u16x8 o;
    o[0]=f2b(a[0]); o[1]=f2b(a[1]); o[2]=f2b(a[2]); o[3]=f2b(a[3]);
    o[4]=f2b(b[0]); o[5]=f2b(b[1]); o[6]=f2b(b[2]); o[7]=f2b(b[3]);
    *(u16x8*)(dst + 8*i) = o;
}

// ---------------- pool x over 8x8 regions (fp32 exact path for routing) ----------------
__global__ __launch_bounds__(256) void k_pool_x(const float* __restrict__ x,
                                                float* __restrict__ xp){
    int blk = blockIdx.x;                 // b*49 + reg
    int b = blk / NREG, reg = blk % NREG;
    int rh = reg / NWIN, rw = reg % NWIN;
    int t = threadIdx.x;
    const float* base = x + ((size_t)b*PPI + (rh*8)*WWD + rw*8) * CCH;
    for (int c = t; c < CCH; c += 256){
        float s = 0.f;
        #pragma unroll
        for (int a = 0; a < 8; a++)
            #pragma unroll
            for (int w2 = 0; w2 < 8; w2++)
                s += base[(a*WWD + w2)*CCH + c];
        xp[(size_t)blk*CCH + c] = s * (1.0f/64.0f);
    }
}

// ---------------- pooled q/k projection as fp32 tiled GEMM ----------------
#define QP_BM 64
#define QP_BN 64
#define QP_BK 32
__global__ __launch_bounds__(256) void k_qk_pool(const float* __restrict__ xp,
                                                 const float* __restrict__ qkv_w,
                                                 const float* __restrict__ qkv_b,
                                                 float* __restrict__ qkp){
    __shared__ float Xs[QP_BK][QP_BM+1];
    __shared__ float Ws[QP_BK][QP_BN+1];
    int bx = blockIdx.x;                  // 7 row-tiles x 16 col-tiles = 112
    int mt = bx >> 4, nt = bx & 15;
    int row0 = mt*QP_BM, o0 = nt*QP_BN;
    int t = threadIdx.x;
    int tx = t & 15, ty = t >> 4;
    float acc[4][4];
    #pragma unroll
    for (int i = 0; i < 4; i++)
        #pragma unroll
        for (int j = 0; j < 4; j++) acc[i][j] = 0.f;

    for (int ks = 0; ks < CCH/QP_BK; ks++){
        int k0 = ks*QP_BK;
        #pragma unroll
        for (int i = 0; i < 8; i++){
            int idx = t + 256*i;          // 2048 elements per tile
            int row = idx >> 5, col = idx & 31;
            int gr = row0 + row;
            Xs[col][row] = (gr < BB*NREG) ? xp[(size_t)gr*CCH + k0 + col] : 0.f;
            Ws[col][row] = qkv_w[(size_t)(o0 + row)*CCH + k0 + col];
        }
        __syncthreads();
        #pragma unroll
        for (int kk = 0; kk < QP_BK; kk++){
            float a[4], bvv[4];
            #pragma unroll
            for (int i = 0; i < 4; i++) a[i] = Xs[kk][ty*4 + i];
            #pragma unroll
            for (int j = 0; j < 4; j++) bvv[j] = Ws[kk][tx*4 + j];
            #pragma unroll
            for (int i = 0; i < 4; i++)
                #pragma unroll
                for (int j = 0; j < 4; j++)
                    acc[i][j] += a[i] * bvv[j];
        }
        __syncthreads();
    }
    #pragma unroll
    for (int i = 0; i < 4; i++){
        int r = row0 + ty*4 + i;
        if (r >= BB*NREG) continue;
        #pragma unroll
        for (int j = 0; j < 4; j++){
            int o = o0 + tx*4 + j;
            qkp[(size_t)r*1024 + o] = acc[i][j] + qkv_b[o];
        }
    }
}

// ---------------- a_r scores + top-4 (fp32, stable tie-break = lowest index) ----------------
__global__ __launch_bounds__(64) void k_route(const float* __restrict__ qkp,
                                              int* __restrict__ idx){
    int blk = blockIdx.x;                 // b*49 + qreg
    int b = blk / NREG;
    int lane = threadIdx.x;
    __shared__ float sc[NREG];
    const float* qr = qkp + (size_t)blk*1024;
    float qv[8];
    #pragma unroll
    for (int i = 0; i < 8; i++) qv[i] = qr[lane + 64*i];
    for (int j = 0; j < NREG; j++){
        const float* kr = qkp + ((size_t)(b*NREG + j)*1024 + 512);
        float p = 0.f;
        #pragma unroll
        for (int i = 0; i < 8; i++) p += qv[i] * kr[lane + 64*i];
        #pragma unroll
        for (int msk = 32; msk >= 1; msk >>= 1) p += __shfl_xor(p, msk, 64);
        if (lane == 0) sc[j] = p;
    }
    __syncthreads();
    if (lane == 0){
        #pragma unroll
        for (int t = 0; t < TOPKK; t++){
            float best = -1e30f; int bj = 0;
            for (int j = 0; j < NREG; j++){
                if (sc[j] > best){ best = sc[j]; bj = j; }
            }
            idx[blk*TOPKK + t] = bj;
            sc[bj] = -1e30f;
        }
    }
}

// ---------------- QKV GEMM: [25088 x 512] x [1536 x 512]^T, scatter into seq layout ----------------
#define BM 128
#define BN 128
#define BK 64
__global__ __launch_bounds__(256) void k_gemm_qkv(const u16* __restrict__ xb,
                                                  const u16* __restrict__ wb,
                                                  const float* __restrict__ bias,
                                                  u16* __restrict__ q_s,
                                                  u16* __restrict__ k_s,
                                                  u16* __restrict__ v_s){
    __shared__ u16 As[BM*BK];
    __shared__ u16 Bs[BN*BK];
    int bx = (blockIdx.x & 7)*294 + (blockIdx.x >> 3);   // XCD-chunked (2352 = 8*294)
    int mt = bx / (OC/BN), nt = bx % (OC/BN);
    int pix0 = mt*BM, o0 = nt*BN;
    int t = threadIdx.x;
    int wid = t >> 6, lane = t & 63;
    int wm = wid >> 1, wn = wid & 1;
    int l15 = lane & 15, hi = lane >> 4;
    f32x4 acc[4][4];
    #pragma unroll
    for (int i = 0; i < 4; i++)
        #pragma unroll
        for (int j = 0; j < 4; j++) acc[i][j] = (f32x4){0.f,0.f,0.f,0.f};

    for (int ks = 0; ks < CCH/BK; ks++){
        int K0 = ks*BK;
        #pragma unroll
        for (int i = 0; i < 4; i++){
            int off = t*16 + i*4096;      // flat byte offset in 16KB tile
            int row = off >> 7;           // 128B per row (64 bf16)
            int cs  = ((off & 127) >> 1) ^ sw8(row);   // pre-swizzled source col
            gld16(xb + (size_t)(pix0+row)*CCH + K0 + cs, (char*)As + off);
            gld16(wb + (size_t)(o0 +row)*CCH + K0 + cs, (char*)Bs + off);
        }
        __syncthreads();
        #pragma unroll
        for (int kk = 0; kk < 2; kk++){
            u16x8 af[4], bf[4];
            #pragma unroll
            for (int i = 0; i < 4; i++){
                int rowA = wm*64 + i*16 + l15;
                af[i] = *(const u16x8*)&As[rowA*BK + ((kk*32 + hi*8) ^ sw8(rowA))];
            }
            #pragma unroll
            for (int j = 0; j < 4; j++){
                int rowB = wn*64 + j*16 + l15;
                bf[j] = *(const u16x8*)&Bs[rowB*BK + ((kk*32 + hi*8) ^ sw8(rowB))];
            }
            #pragma unroll
            for (int i = 0; i < 4; i++)
                #pragma unroll
                for (int j = 0; j < 4; j++)
                    acc[i][j] = MFMA(af[i], bf[j], acc[i][j]);
        }
        __syncthreads();
    }
    // epilogue: scatter into q_s/k_s/v_s seq layout [b][head][reg][pix][d], add bias
    #pragma unroll
    for (int i = 0; i < 4; i++){
        int prow_base = pix0 + wm*64 + i*16 + 4*hi;
        #pragma unroll
        for (int j = 0; j < 4; j++){
            int o = o0 + wn*64 + j*16 + l15;
            int which = o >> 9;
            int c = o & 511;
            int m = c >> 6, d = c & 63;
            float bv = bias[o];
            u16* dst = (which == 0) ? q_s : (which == 1) ? k_s : v_s;
            #pragma unroll
            for (int r = 0; r < 4; r++){
                int pix = prow_base + r;
                int b  = pix / PPI;
                int pp = pix - b*PPI;
                int h  = pp / WWD, w2 = pp - h*WWD;
                int reg = (h >> 3)*NWIN + (w2 >> 3);
                int pr  = (h & 7)*8 + (w2 & 7);
                size_t oi = (((size_t)(b*NHEADS + m)*NREG + reg)*RSZ + pr)*HD + d;
                dst[oi] = f2b(acc[i][j][r] + bv);
            }
        }
    }
}

// ---------------- fused attention + LEPE: block = (b, head, qreg), writes bf16 yb ----------------
__global__ __launch_bounds__(256) void k_attn(const u16* __restrict__ q_s,
                                              const u16* __restrict__ k_s,
                                              const u16* __restrict__ v_s,
                                              const int* __restrict__ idx,
                                              const float* __restrict__ lw,
                                              const float* __restrict__ lb,
                                              u16* __restrict__ yb){
    __shared__ u16 Ks[256*64];   // swizzled [key][64]; reused as swizzled P[64][256]
    __shared__ u16 Vt[64*256];   // swizzled [d][256]; reused as lepe halo after PV
    __shared__ float Wl[64*9];   // lepe weights for this head
    __shared__ float Bl[64];     // lepe bias for this head
    int bid = (blockIdx.x & 7)*392 + (blockIdx.x >> 3);  // XCD-chunked (3136 = 8*392)
    int b  = bid / (NHEADS*NREG);
    int r2 = bid % (NHEADS*NREG);
    int m = r2 / NREG, qreg = r2 % NREG;
    int rh = qreg / NWIN, rw = qreg % NWIN;
    int t = threadIdx.x, wid = t >> 6, lane = t & 63;
    int l15 = lane & 15, hi = lane >> 4;

    size_t hb = (size_t)(b*NHEADS + m)*NREG;
    int i4[4];
    #pragma unroll
    for (int j = 0; j < 4; j++) i4[j] = idx[(b*NREG + qreg)*TOPKK + j];

    // issue lepe halo loads early (10x10 cells x 64 d, 8 d per chunk -> 800 chunks)
    u16x8 halo0 = (u16x8){0,0,0,0,0,0,0,0}, halo1 = halo0, halo2 = halo0, halo3 = halo0;
    #pragma unroll
    for (int i = 0; i < 4; i++){
        int c = t + 256*i;
        if (c < 800){
            int cell = c >> 3, part = c & 7;
            int hr = cell / 10, wc = cell % 10;
            int hh2 = rh*8 - 1 + hr, ww2 = rw*8 - 1 + wc;
            if (hh2 >= 0 && hh2 < HH && ww2 >= 0 && ww2 < WWD){
                int reg2 = (hh2 >> 3)*NWIN + (ww2 >> 3);
                int pr2  = (hh2 & 7)*8 + (ww2 & 7);
                u16x8 v8 = *(const u16x8*)&v_s[((hb + reg2)*RSZ + pr2)*HD + part*8];
                if (i == 0) halo0 = v8; else if (i == 1) halo1 = v8;
                else if (i == 2) halo2 = v8; else halo3 = v8;
            }
        }
    }
    // stage lepe weights/bias
    for (int i = t; i < 64*9; i += 256) Wl[i] = lw[(m*64 + i/9)*9 + (i%9)];
    if (t < 64) Bl[t] = lb[m*64 + t];

    // stage K via global_load_lds, content-swizzled through the source column
    #pragma unroll
    for (int i = 0; i < 8; i++){
        int off = t*16 + i*4096;
        int rsel = off >> 13;
        int row  = off >> 7;                       // key 0..255
        int cs   = ((off & 127) >> 1) ^ sw8(row);
        gld16(k_s + (hb + i4[rsel])*(RSZ*HD) + (size_t)(row & 63)*HD + cs,
              (char*)Ks + off);
    }
    // stage V transposed: coalesced global read -> swizzled scalar LDS scatter
    #pragma unroll
    for (int i = 0; i < 8; i++){
        int off = t*16 + i*4096;
        int rsel = off >> 13;
        int key = off >> 7;
        int d0  = (off & 127) >> 1;
        const u16* src = v_s + (hb + i4[rsel])*(RSZ*HD) + (size_t)(key & 63)*HD + d0;
        u16x8 v = *(const u16x8*)src;
        #pragma unroll
        for (int jj = 0; jj < 8; jj++){
            int row = d0 + jj;
            Vt[row*256 + (key ^ sw8(row))] = v[jj];
        }
    }
    // q fragments straight from global (wave strip = rows wid*16..+16)
    const u16* qb = q_s + (hb + qreg)*(RSZ*HD);
    u16x8 aq[2];
    #pragma unroll
    for (int kk = 0; kk < 2; kk++)
        aq[kk] = *(const u16x8*)&qb[(wid*16 + l15)*HD + kk*32 + hi*8];
    __syncthreads();

    // QK^T: wave computes its 16-row strip x all 256 keys
    f32x4 s[16];
    #pragma unroll
    for (int fn = 0; fn < 16; fn++) s[fn] = (f32x4){0.f,0.f,0.f,0.f};
    #pragma unroll
    for (int kk = 0; kk < 2; kk++)
        #pragma unroll
        for (int fn = 0; fn < 16; fn++){
            int rowK = fn*16 + l15;
            u16x8 bf = *(const u16x8*)&Ks[rowK*HD + ((kk*32 + hi*8) ^ sw8(rowK))];
            s[fn] = MFMA(aq[kk], bf, s[fn]);
        }
    // scale + in-register softmax (row r lives in lanes with same hi, across l15 x fn)
    #pragma unroll
    for (int fn = 0; fn < 16; fn++)
        #pragma unroll
        for (int rr = 0; rr < 4; rr++) s[fn][rr] *= SCALE_F;
    float inv[4];
    #pragma unroll
    for (int rr = 0; rr < 4; rr++){
        float v = s[0][rr];
        #pragma unroll
        for (int fn = 1; fn < 16; fn++) v = fmaxf(v, s[fn][rr]);
        #pragma unroll
        for (int msk = 1; msk < 16; msk <<= 1) v = fmaxf(v, __shfl_xor(v, msk, 64));
        float ss = 0.f;
        #pragma unroll
        for (int fn = 0; fn < 16; fn++){
            float e = __expf(s[fn][rr] - v);
            s[fn][rr] = e; ss += e;
        }
        #pragma unroll
        for (int msk = 1; msk < 16; msk <<= 1) ss += __shfl_xor(ss, msk, 64);
        inv[rr] = 1.0f / ss;
    }
    __syncthreads();               // all waves done reading Ks
    // write P (bf16) into Ks region as swizzled [64][256]
    #pragma unroll
    for (int fn = 0; fn < 16; fn++)
        #pragma unroll
        for (int rr = 0; rr < 4; rr++){
            int rowP = wid*16 + 4*hi + rr;
            Ks[rowP*256 + ((fn*16 + l15) ^ sw8(rowP))] = f2b(s[fn][rr]*inv[rr]);
        }
    __syncthreads();
    // PV: strip rows x 64 d, K=256
    f32x4 o[4];
    #pragma unroll
    for (int j = 0; j < 4; j++) o[j] = (f32x4){0.f,0.f,0.f,0.f};
    #pragma unroll
    for (int ksx = 0; ksx < 8; ksx++){
        int rowP = wid*16 + l15;
        u16x8 pa = *(const u16x8*)&Ks[rowP*256 + ((ksx*32 + hi*8) ^ sw8(rowP))];
        #pragma unroll
        for (int j = 0; j < 4; j++){
            int rowV = j*16 + l15;
            u16x8 vb = *(const u16x8*)&Vt[rowV*256 + ((ksx*32 + hi*8) ^ sw8(rowV))];
            o[j] = MFMA(pa, vb, o[j]);
        }
    }
    __syncthreads();               // Vt no longer needed; reuse for halo
    // halo -> LDS, padded cell stride 72 u16 (144B: 16B-aligned, bank-disjoint groups)
    #pragma unroll
    for (int i = 0; i < 4; i++){
        int c = t + 256*i;
        if (c < 800){
            int cell = c >> 3, part = c & 7;
            u16x8 v8 = (i == 0) ? halo0 : (i == 1) ? halo1 : (i == 2) ? halo2 : halo3;
            *(u16x8*)&Vt[cell*72 + part*8] = v8;
        }
    }
    __syncthreads();
    // lepe + output: thread covers row a_row, cols col0..col0+3, channels j*16+l15
    int a_row = wid*2 + (hi >> 1);
    int col0  = (hi & 1)*4;
    #pragma unroll
    for (int j = 0; j < 4; j++){
        int d = j*16 + l15;
        float w9[9];
        #pragma unroll
        for (int tap = 0; tap < 9; tap++) w9[tap] = Wl[d*9 + tap];
        float bias = Bl[d];
        #pragma unroll
        for (int rr = 0; rr < 4; rr++){
            int col = col0 + rr;
            float acc = bias;
            #pragma unroll
            for (int kh = 0; kh < 3; kh++)
                #pragma unroll
                for (int kw = 0; kw < 3; kw++)
                    acc += b2f(Vt[((a_row + kh)*10 + (col + kw))*72 + d]) * w9[kh*3 + kw];
            float val = o[j][rr] + acc;
            int h = rh*8 + a_row, w2c = rw*8 + col;
            yb[((size_t)b*PPI + h*WWD + w2c)*CCH + m*HD + d] = f2b(val);
        }
    }
}

// ---------------- output GEMM: [25088 x 512] x [512 x 512]^T -> fp32 NHWC ----------------
__global__ __launch_bounds__(256) void k_gemm_out(const u16* __restrict__ yb,
                                                  const u16* __restrict__ wb,
                                                  const float* __restrict__ bias,
                                                  float* __restrict__ out){
    __shared__ u16 As[BM*BK];
    __shared__ u16 Bs[BN*BK];
    int bx = (blockIdx.x & 7)*98 + (blockIdx.x >> 3);    // XCD-chunked (784 = 8*98)
    int mt = bx >> 2, nt = bx & 3;
    int pix0 = mt*BM, o0 = nt*BN;
    int t = threadIdx.x;
    int wid = t >> 6, lane = t & 63;
    int wm = wid >> 1, wn = wid & 1;
    int l15 = lane & 15, hi = lane >> 4;
    f32x4 acc[4][4];
    #pragma unroll
    for (int i = 0; i < 4; i++)
        #pragma unroll
        for (int j = 0; j < 4; j++) acc[i][j] = (f32x4){0.f,0.f,0.f,0.f};

    for (int ks = 0; ks < CCH/BK; ks++){
        int K0 = ks*BK;
        #pragma unroll
        for (int i = 0; i < 4; i++){
            int off = t*16 + i*4096;
            int row = off >> 7;
            int cs  = ((off & 127) >> 1) ^ sw8(row);
            gld16(yb + (size_t)(pix0+row)*CCH + K0 + cs, (char*)As + off);
            gld16(wb + (size_t)(o0 +row)*CCH + K0 + cs, (char*)Bs + off);
        }
        __syncthreads();
        #pragma unroll
        for (int kk = 0; kk < 2; kk++){
            u16x8 af[4], bf[4];
            #pragma unroll
            for (int i = 0; i < 4; i++){
                int rowA = wm*64 + i*16 + l15;
                af[i] = *(const u16x8*)&As[rowA*BK + ((kk*32 + hi*8) ^ sw8(rowA))];
            }
            #pragma unroll
            for (int j = 0; j < 4; j++){
                int rowB = wn*64 + j*16 + l15;
                bf[j] = *(const u16x8*)&Bs[rowB*BK + ((kk*32 + hi*8) ^ sw8(rowB))];
            }
            #pragma unroll
            for (int i = 0; i < 4; i++)
                #pragma unroll
                for (int j = 0; j < 4; j++)
                    acc[i][j] = MFMA(af[i], bf[j], acc[i][j]);
        }
        __syncthreads();
    }
    #pragma unroll
    for (int i = 0; i < 4; i++){
        #pragma unroll
        for (int j = 0; j < 4; j++){
            int o = o0 + wn*64 + j*16 + l15;
            float bv = bias[o];
            #pragma unroll
            for (int r = 0; r < 4; r++){
                int pix = pix0 + wm*64 + i*16 + 4*hi + r;
                out[(size_t)pix*CCH + o] = acc[i][j][r] + bv;
            }
        }
    }
}

// ---------------- launch ----------------
extern "C" void kernel_launch(void* const* d_in, const int* in_sizes, int n_in,
                              void* d_out, int out_size, void* d_ws, size_t ws_size,
                              hipStream_t stream){
    const float* x      = (const float*)d_in[0];
    const float* qkv_w  = (const float*)d_in[1];
    const float* qkv_b  = (const float*)d_in[2];
    const float* lepe_w = (const float*)d_in[3];
    const float* lepe_b = (const float*)d_in[4];
    const float* out_w  = (const float*)d_in[5];
    const float* out_b  = (const float*)d_in[6];

    char* w = (char*)d_ws;
    u16*   xb   = (u16*)(w + 0);            // 25,690,112
    u16*   wqkv = (u16*)(w + 25690112);     //  1,572,864
    u16*   wout = (u16*)(w + 27262976);     //    524,288
    u16*   q_s  = (u16*)(w + 27787264);     // 25,690,112
    u16*   k_s  = (u16*)(w + 53477376);     // 25,690,112
    u16*   v_s  = (u16*)(w + 79167488);     // 25,690,112
    float* xp   = (float*)(w + 104857600);  //    802,816
    float* qkp  = (float*)(w + 105660416);  //  1,605,632
    int*   idx  = (int*)(w + 107266048);    //      6,272
    u16*   yb   = (u16*)(w + 107272320);    // 25,690,112

    k_f32_to_bf16<<<dim3(6272), dim3(256), 0, stream>>>(x, xb, NPIX*CCH/8);
    k_f32_to_bf16<<<dim3(384),  dim3(256), 0, stream>>>(qkv_w, wqkv, OC*CCH/8);
    k_f32_to_bf16<<<dim3(128),  dim3(256), 0, stream>>>(out_w, wout, CCH*CCH/8);
    k_pool_x<<<dim3(BB*NREG), dim3(256), 0, stream>>>(x, xp);
    k_qk_pool<<<dim3(112), dim3(256), 0, stream>>>(xp, qkv_w, qkv_b, qkp);
    k_route<<<dim3(BB*NREG), dim3(64), 0, stream>>>(qkp, idx);
    k_gemm_qkv<<<dim3((NPIX/BM)*(OC/BN)), dim3(256), 0, stream>>>(xb, wqkv, qkv_b, q_s, k_s, v_s);
    k_attn<<<dim3(BB*NHEADS*NREG), dim3(256), 0, stream>>>(q_s, k_s, v_s, idx, lepe_w, lepe_b, yb);
    k_gemm_out<<<dim3((NPIX/BM)*(CCH/BN)), dim3(256), 0, stream>>>(yb, wout, out_b, (float*)d_out);
}